// Round 4
// baseline (350.851 us; speedup 1.0000x reference)
//
#include <hip/hip_runtime.h>
#include <stdint.h>

// LorentzLinear fused: y = x @ W^T + b ; time = sigmoid(y0)*e^scale + 1.1 ;
// out = [time, y_narrow * sqrt((time^2-1)/max(sum(y_narrow^2),1e-8))]
// M=65536, K=512, N=512.
// R3: counted-vmcnt double buffer, BK=32, 16 iters.
//  - x: reg-pipeline 2 tiles ahead (issue@kt for kt+2, cvt+write@kt for kt+1)
//  - W: gload_lds issued at top of iter, gated by vmcnt(1) pre-barrier only
//  - layouts [k-half][col/row][16B] -> all frag ds_read_b128 lane-contiguous
//  - wave tile 64x64 (8 n-slices), 8 ds_read + 8 MFMA(32x32x16) per iter

typedef short short8 __attribute__((ext_vector_type(8)));
typedef float f32x16 __attribute__((ext_vector_type(16)));
typedef unsigned short ushort4v __attribute__((ext_vector_type(4)));

#define THREADS 512
#define BM 64
#define KTILES 16                 // 512 / 32
#define WTILE 32768               // 4 kh x 512 col x 16B
#define XPAD 1056                 // 66 x 16B  (pad spreads stage-write banks)
#define XTILE (4 * XPAD)          // 4224
#define PHASE (WTILE + XTILE)     // 36992 ; x2 = 73984 -> 2 blocks/CU

__device__ __forceinline__ unsigned short f2bf(float f) {
  union { float f; uint32_t u; } v; v.f = f;
  uint32_t u = v.u;
  return (unsigned short)((u + 0x7FFFu + ((u >> 16) & 1u)) >> 16);  // RNE
}

__device__ __forceinline__ void gload_lds16(const void* g, void* l) {
  __builtin_amdgcn_global_load_lds(
      (const __attribute__((address_space(1))) void*)g,
      (__attribute__((address_space(3))) void*)l, 16, 0, 0);
}

// W fp32 -> bf16 once per launch (d_ws re-poisoned every run)
__global__ void wconv_kernel(const float* __restrict__ w,
                             unsigned short* __restrict__ wb) {
  const int i = (blockIdx.x * blockDim.x + threadIdx.x) * 4;
  float4 f = *(const float4*)(w + i);
  ushort4v h;
  h[0] = f2bf(f.x); h[1] = f2bf(f.y); h[2] = f2bf(f.z); h[3] = f2bf(f.w);
  *(ushort4v*)(wb + i) = h;
}

__global__ __launch_bounds__(THREADS, 4) void lorentz_kernel(
    const float* __restrict__ xg, const unsigned short* __restrict__ wb,
    const float* __restrict__ bg, const float* __restrict__ sg,
    float* __restrict__ out) {
  __shared__ __align__(16) char smem[2 * PHASE];
  const int t = threadIdx.x;
  const int lane = t & 63;
  const int wn = t >> 6;          // 0..7 : 64-col slice
  const int l31 = lane & 31;
  const int h = lane >> 5;
  const int bm = blockIdx.x * BM;

  char* const B0 = smem;
  char* const B1 = smem + PHASE;

  // W stage: iter i: dest = i*8192 + t*16  -> kh=i, col=t
  //          src   = wb[col=t][kt*32 + i*8 ..+8]
  const unsigned short* wsrc0 = wb + t * 512;
  const int wdst = t * 16;
  // x stage: thread t: row=t>>3, 4 fp32 at k = kt*32 + (t&7)*4
  const float* xsrc0 = xg + (size_t)(bm + (t >> 3)) * 512 + (t & 7) * 4;
  const int xdst = ((t & 7) >> 1) * XPAD + (t >> 3) * 16 + (t & 1) * 8;
  // frag bases
  const int abase = h * XPAD + l31 * 16;                 // + ks*2*XPAD + mr*512
  const int bbase = h * 8192 + (wn * 64 + l31) * 16;     // + ks*16384 + nr*512

  f32x16 acc[2][2];
  #pragma unroll
  for (int a = 0; a < 2; ++a)
    #pragma unroll
    for (int n = 0; n < 2; ++n)
      #pragma unroll
      for (int j = 0; j < 16; ++j) acc[a][n][j] = 0.f;

  float4 xrA, xrB;

  // ---- prologue: tile 0 fully staged -> B0 ; x(1) issued -> xrB ----
  {
    float4 x0 = *(const float4*)(xsrc0);           // x(0)
    #pragma unroll
    for (int i = 0; i < 4; ++i)
      gload_lds16(wsrc0 + i * 8, B0 + i * 8192 + wdst);
    uint2 p;
    p.x = (uint32_t)f2bf(x0.x) | ((uint32_t)f2bf(x0.y) << 16);
    p.y = (uint32_t)f2bf(x0.z) | ((uint32_t)f2bf(x0.w) << 16);
    *(uint2*)(B0 + WTILE + xdst) = p;
    xrB = *(const float4*)(xsrc0 + 32);            // x(1)
    asm volatile("s_waitcnt vmcnt(1) lgkmcnt(0)" ::: "memory");
    __builtin_amdgcn_s_barrier();
  }

  auto body = [&](int kt, char* cur, char* nxt, float4& xr_issue,
                  float4& xr_cvt) {
    // 1: W(kt+1) -> nxt (full-body window until pre-barrier vmcnt gate)
    if (kt < 15) {
      const unsigned short* ws = wsrc0 + (kt + 1) * 32;
      #pragma unroll
      for (int i = 0; i < 4; ++i)
        gload_lds16(ws + i * 8, nxt + i * 8192 + wdst);
    }
    // 2: issue x(kt+2) (consumed next iteration)
    if (kt < 14) xr_issue = *(const float4*)(xsrc0 + (kt + 2) * 32);
    // 3+4: frags + MFMA
    const char* xb = cur + WTILE;
    __builtin_amdgcn_s_setprio(1);
    #pragma unroll
    for (int ks = 0; ks < 2; ++ks) {
      const short8 a0 = *(const short8*)(xb + abase + ks * 2 * XPAD);
      const short8 a1 = *(const short8*)(xb + abase + ks * 2 * XPAD + 512);
      const short8 b0 = *(const short8*)(cur + bbase + ks * 16384);
      const short8 b1 = *(const short8*)(cur + bbase + ks * 16384 + 512);
      acc[0][0] = __builtin_amdgcn_mfma_f32_32x32x16_bf16(a0, b0, acc[0][0], 0, 0, 0);
      acc[0][1] = __builtin_amdgcn_mfma_f32_32x32x16_bf16(a0, b1, acc[0][1], 0, 0, 0);
      acc[1][0] = __builtin_amdgcn_mfma_f32_32x32x16_bf16(a1, b0, acc[1][0], 0, 0, 0);
      acc[1][1] = __builtin_amdgcn_mfma_f32_32x32x16_bf16(a1, b1, acc[1][1], 0, 0, 0);
    }
    __builtin_amdgcn_s_setprio(0);
    // 5: cvt x(kt+1) (loaded LAST iter; implicit wait leaves this iter's
    //    5 loads in flight) -> nxt x-region
    if (kt < 15) {
      uint2 p;
      p.x = (uint32_t)f2bf(xr_cvt.x) | ((uint32_t)f2bf(xr_cvt.y) << 16);
      p.y = (uint32_t)f2bf(xr_cvt.z) | ((uint32_t)f2bf(xr_cvt.w) << 16);
      *(uint2*)(nxt + WTILE + xdst) = p;
    }
    // 6: counted gate: W(kt+1) landed, x(kt+2) may fly. Never vmcnt(0)
    //    until the last staging iteration.
    if (kt < 14)
      asm volatile("s_waitcnt vmcnt(1) lgkmcnt(0)" ::: "memory");
    else if (kt == 14)
      asm volatile("s_waitcnt vmcnt(0) lgkmcnt(0)" ::: "memory");
    else
      asm volatile("s_waitcnt lgkmcnt(0)" ::: "memory");
    if (kt < 15) __builtin_amdgcn_s_barrier();
  };

  for (int k2 = 0; k2 < KTILES; k2 += 2) {
    body(k2, B0, B1, xrA, xrB);
    body(k2 + 1, B1, B0, xrB, xrA);
  }

  // ---------------- epilogue ----------------
  // acc[mr][nr][j] = y[bm + mr*32 + (j&3)+8*(j>>2)+4*h][wn*64 + nr*32 + l31]
  const float esc = __expf(sg[0]);
  float bv[2];
  #pragma unroll
  for (int nr = 0; nr < 2; ++nr) bv[nr] = bg[wn * 64 + nr * 32 + l31];
  #pragma unroll
  for (int mr = 0; mr < 2; ++mr)
    #pragma unroll
    for (int nr = 0; nr < 2; ++nr)
      #pragma unroll
      for (int j = 0; j < 16; ++j)
        acc[mr][nr][j] += bv[nr];

  const bool c0 = (wn == 0) && (l31 == 0);   // nr==0 col is global col 0
  float ss[2][16];
  #pragma unroll
  for (int mr = 0; mr < 2; ++mr)
    #pragma unroll
    for (int j = 0; j < 16; ++j) {
      float s = 0.f;
      #pragma unroll
      for (int nr = 0; nr < 2; ++nr) { const float v = acc[mr][nr][j]; s += v * v; }
      if (c0) { const float v = acc[mr][0][j]; s -= v * v; }   // exclude y0
      ss[mr][j] = s;
    }
  #pragma unroll
  for (int m = 1; m < 32; m <<= 1)
    #pragma unroll
    for (int mr = 0; mr < 2; ++mr)
      #pragma unroll
      for (int j = 0; j < 16; ++j)
        ss[mr][j] += __shfl_xor(ss[mr][j], m, 64);

  float* red = (float*)smem;           // B0 region (dead: last reads hit B1)
  float* tsh = (float*)(smem + 256);
  if (t < 64) red[t] = 0.f;
  __syncthreads();
  if (l31 == 0) {                      // lanes 0 and 32
    #pragma unroll
    for (int mr = 0; mr < 2; ++mr)
      #pragma unroll
      for (int j = 0; j < 16; ++j) {
        const int r = mr * 32 + (j & 3) + 8 * (j >> 2) + 4 * h;
        atomicAdd(&red[r], ss[mr][j]);
      }
  }
  if (c0) {
    #pragma unroll
    for (int mr = 0; mr < 2; ++mr)
      #pragma unroll
      for (int j = 0; j < 16; ++j) {
        const int r = mr * 32 + (j & 3) + 8 * (j >> 2) + 4 * h;
        const float y0 = acc[mr][0][j];
        tsh[r] = esc / (1.f + __expf(-y0)) + 1.1f;
      }
  }
  __syncthreads();

  #pragma unroll
  for (int mr = 0; mr < 2; ++mr)
    #pragma unroll
    for (int g = 0; g < 4; ++g) {
      const int rbase = mr * 32 + 8 * g + 4 * h;
      const float4 r4 = *(const float4*)(red + rbase);
      const float4 t4 = *(const float4*)(tsh + rbase);
      #pragma unroll
      for (int j = 0; j < 4; ++j) {
        float denom = (&r4.x)[j];
        denom = denom < 1e-8f ? 1e-8f : denom;
        const float tt = (&t4.x)[j];
        const float coef = sqrtf((tt * tt - 1.f) / denom);
        float* orow = out + (size_t)(bm + rbase + j) * 512;
        #pragma unroll
        for (int nr = 0; nr < 2; ++nr) {
          const int c = wn * 64 + nr * 32 + l31;
          orow[c] = (c == 0) ? tt : acc[mr][nr][4 * g + j] * coef;
        }
      }
    }
}

extern "C" void kernel_launch(void* const* d_in, const int* in_sizes, int n_in,
                              void* d_out, int out_size, void* d_ws, size_t ws_size,
                              hipStream_t stream) {
  const float* x = (const float*)d_in[0];
  const float* W = (const float*)d_in[1];
  const float* b = (const float*)d_in[2];
  const float* sc = (const float*)d_in[3];
  float* outp = (float*)d_out;
  unsigned short* wb = (unsigned short*)d_ws;   // 512*512*2 = 512KB scratch

  wconv_kernel<<<256, 256, 0, stream>>>(W, wb);
  lorentz_kernel<<<65536 / BM, THREADS, 0, stream>>>(x, wb, b, sc, outp);
}

// Round 5
// 349.146 us; speedup vs baseline: 1.0049x; 1.0049x over previous
//
#include <hip/hip_runtime.h>
#include <stdint.h>

// LorentzLinear fused: y = x @ W^T + b ; time = sigmoid(y0)*e^scale + 1.1 ;
// out = [time, y_narrow * sqrt((time^2-1)/max(sum(y_narrow^2),1e-8))]
// M=65536, K=512, N=512.
// R4: back to compiler-scheduled structure (R1 lesson: manual vmcnt/setprio
// cost 2x). x staged to LDS per half-K (NOT in the K-loop); steady-state
// body = 2 gload_lds (W) + 4 ds_read_b128 + 4 MFMA(32x32x16) + syncthreads,
// fully unrolled. LDS 64KB -> 2 blocks/CU.

typedef short short8 __attribute__((ext_vector_type(8)));
typedef float f32x16 __attribute__((ext_vector_type(16)));
typedef unsigned short ushort4v __attribute__((ext_vector_type(4)));
typedef unsigned short ushort8v __attribute__((ext_vector_type(8)));

#define THREADS 512
#define BM 64
#define WBUF(i) ((i) * 16384)     // 2 x 16KB: [kh(2)][col(512)][16B]
#define XBASE 32768               // 32KB: [row(64)][512B], XOR-swizzled
// LDS total 65536 -> 2 blocks/CU

__device__ __forceinline__ unsigned short f2bf(float f) {
  union { float f; uint32_t u; } v; v.f = f;
  uint32_t u = v.u;
  return (unsigned short)((u + 0x7FFFu + ((u >> 16) & 1u)) >> 16);  // RNE
}

__device__ __forceinline__ void gload_lds16(const void* g, void* l) {
  __builtin_amdgcn_global_load_lds(
      (const __attribute__((address_space(1))) void*)g,
      (__attribute__((address_space(3))) void*)l, 16, 0, 0);
}

// W fp32 -> bf16 once per launch (d_ws re-poisoned every run)
__global__ void wconv_kernel(const float* __restrict__ w,
                             unsigned short* __restrict__ wb) {
  const int i = (blockIdx.x * blockDim.x + threadIdx.x) * 4;
  float4 f = *(const float4*)(w + i);
  ushort4v h;
  h[0] = f2bf(f.x); h[1] = f2bf(f.y); h[2] = f2bf(f.z); h[3] = f2bf(f.w);
  *(ushort4v*)(wb + i) = h;
}

__global__ __launch_bounds__(THREADS, 4) void lorentz_kernel(
    const float* __restrict__ xg, const unsigned short* __restrict__ wb,
    const float* __restrict__ bg, const float* __restrict__ sg,
    float* __restrict__ out) {
  __shared__ __align__(16) char smem[65536];
  const int t = threadIdx.x;
  const int lane = t & 63;
  const int wn = t >> 6;          // 0..7 : 64-col slice
  const int l31 = lane & 31;
  const int h = lane >> 5;
  const int bm = blockIdx.x * BM;
  const int swz = (l31 & 7) << 4;

  // W staging: thread t = col; per kt 2 gload_lds (kh=0,1), linear dest.
  const unsigned short* wsrc0 = wb + t * 512;
  // x staging: thread t: row = t>>3, slots (t&7)+8p (slot = 16B = 8 k)
  const int xrow = t >> 3;
  const float* xsrc0 = xg + (size_t)(bm + xrow) * 512 + (t & 7) * 8;
  char* const xdst0 = smem + XBASE + xrow * 512;
  const int xr7 = (xrow & 7) << 4;

  auto stage_x = [&](int half) {
    // load all 8 float4 first, then convert+write (loads pipeline in vmcnt q)
    float4 f[8];
    #pragma unroll
    for (int p = 0; p < 4; ++p) {
      f[2 * p]     = *(const float4*)(xsrc0 + half * 256 + p * 64);
      f[2 * p + 1] = *(const float4*)(xsrc0 + half * 256 + p * 64 + 4);
    }
    #pragma unroll
    for (int p = 0; p < 4; ++p) {
      ushort8v hh;
      hh[0] = f2bf(f[2 * p].x); hh[1] = f2bf(f[2 * p].y);
      hh[2] = f2bf(f[2 * p].z); hh[3] = f2bf(f[2 * p].w);
      hh[4] = f2bf(f[2 * p + 1].x); hh[5] = f2bf(f[2 * p + 1].y);
      hh[6] = f2bf(f[2 * p + 1].z); hh[7] = f2bf(f[2 * p + 1].w);
      const int slotb = ((t & 7) + 8 * p) * 16;
      *(ushort8v*)(xdst0 + (slotb ^ xr7)) = hh;
    }
  };

  auto stage_w = [&](int kt) {
    char* wd = smem + WBUF(kt & 1) + t * 16;
    const unsigned short* ws = wsrc0 + kt * 16;
    gload_lds16(ws, wd);
    gload_lds16(ws + 8, wd + 8192);
  };

  f32x16 acc[2][2];
  #pragma unroll
  for (int a = 0; a < 2; ++a)
    #pragma unroll
    for (int n = 0; n < 2; ++n)
      #pragma unroll
      for (int j = 0; j < 16; ++j) acc[a][n][j] = 0.f;

  auto compute = [&](int kt) {
    const char* wbuf = smem + WBUF(kt & 1);
    const char* xb = smem + XBASE;
    const int ko = (kt & 15) * 32 + h * 16;
    const short8 a0 = *(const short8*)(xb + l31 * 512 + (ko ^ swz));
    const short8 a1 = *(const short8*)(xb + (l31 + 32) * 512 + (ko ^ swz));
    const char* wp = wbuf + h * 8192 + (wn * 64 + l31) * 16;
    const short8 b0 = *(const short8*)(wp);
    const short8 b1 = *(const short8*)(wp + 512);
    acc[0][0] = __builtin_amdgcn_mfma_f32_32x32x16_bf16(a0, b0, acc[0][0], 0, 0, 0);
    acc[0][1] = __builtin_amdgcn_mfma_f32_32x32x16_bf16(a0, b1, acc[0][1], 0, 0, 0);
    acc[1][0] = __builtin_amdgcn_mfma_f32_32x32x16_bf16(a1, b0, acc[1][0], 0, 0, 0);
    acc[1][1] = __builtin_amdgcn_mfma_f32_32x32x16_bf16(a1, b1, acc[1][1], 0, 0, 0);
  };

  // prologue
  stage_x(0);
  stage_w(0);
  __syncthreads();

  #pragma unroll
  for (int kt = 0; kt < 32; ++kt) {
    if (kt == 16) { stage_x(1); __syncthreads(); }
    if (kt < 31) stage_w(kt + 1);
    compute(kt);
    __syncthreads();
  }

  // ---------------- epilogue ----------------
  // acc[mr][nr][j] = y[bm + mr*32 + (j&3)+8*(j>>2)+4*h][wn*64 + nr*32 + l31]
  const float esc = __expf(sg[0]);
  float bv[2];
  #pragma unroll
  for (int nr = 0; nr < 2; ++nr) bv[nr] = bg[wn * 64 + nr * 32 + l31];
  #pragma unroll
  for (int mr = 0; mr < 2; ++mr)
    #pragma unroll
    for (int nr = 0; nr < 2; ++nr)
      #pragma unroll
      for (int j = 0; j < 16; ++j)
        acc[mr][nr][j] += bv[nr];

  const bool c0 = (wn == 0) && (l31 == 0);   // nr==0 col is global col 0
  float ss[2][16];
  #pragma unroll
  for (int mr = 0; mr < 2; ++mr)
    #pragma unroll
    for (int j = 0; j < 16; ++j) {
      float s = 0.f;
      #pragma unroll
      for (int nr = 0; nr < 2; ++nr) { const float v = acc[mr][nr][j]; s += v * v; }
      if (c0) { const float v = acc[mr][0][j]; s -= v * v; }   // exclude y0
      ss[mr][j] = s;
    }
  #pragma unroll
  for (int m = 1; m < 32; m <<= 1)
    #pragma unroll
    for (int mr = 0; mr < 2; ++mr)
      #pragma unroll
      for (int j = 0; j < 16; ++j)
        ss[mr][j] += __shfl_xor(ss[mr][j], m, 64);

  float* red = (float*)smem;           // W-buf region dead after final barrier
  float* tsh = (float*)(smem + 256);
  if (t < 64) red[t] = 0.f;
  __syncthreads();
  if (l31 == 0) {                      // lanes 0 and 32
    #pragma unroll
    for (int mr = 0; mr < 2; ++mr)
      #pragma unroll
      for (int j = 0; j < 16; ++j) {
        const int r = mr * 32 + (j & 3) + 8 * (j >> 2) + 4 * h;
        atomicAdd(&red[r], ss[mr][j]);
      }
  }
  if (c0) {
    #pragma unroll
    for (int mr = 0; mr < 2; ++mr)
      #pragma unroll
      for (int j = 0; j < 16; ++j) {
        const int r = mr * 32 + (j & 3) + 8 * (j >> 2) + 4 * h;
        const float y0 = acc[mr][0][j];
        tsh[r] = esc / (1.f + __expf(-y0)) + 1.1f;
      }
  }
  __syncthreads();

  #pragma unroll
  for (int mr = 0; mr < 2; ++mr)
    #pragma unroll
    for (int g = 0; g < 4; ++g) {
      const int rbase = mr * 32 + 8 * g + 4 * h;
      const float4 r4 = *(const float4*)(red + rbase);
      const float4 t4 = *(const float4*)(tsh + rbase);
      #pragma unroll
      for (int j = 0; j < 4; ++j) {
        float denom = (&r4.x)[j];
        denom = denom < 1e-8f ? 1e-8f : denom;
        const float tt = (&t4.x)[j];
        const float coef = sqrtf((tt * tt - 1.f) / denom);
        float* orow = out + (size_t)(bm + rbase + j) * 512;
        #pragma unroll
        for (int nr = 0; nr < 2; ++nr) {
          const int c = wn * 64 + nr * 32 + l31;
          orow[c] = (c == 0) ? tt : acc[mr][nr][4 * g + j] * coef;
        }
      }
    }
}

extern "C" void kernel_launch(void* const* d_in, const int* in_sizes, int n_in,
                              void* d_out, int out_size, void* d_ws, size_t ws_size,
                              hipStream_t stream) {
  const float* x = (const float*)d_in[0];
  const float* W = (const float*)d_in[1];
  const float* b = (const float*)d_in[2];
  const float* sc = (const float*)d_in[3];
  float* outp = (float*)d_out;
  unsigned short* wb = (unsigned short*)d_ws;   // 512*512*2 = 512KB scratch

  wconv_kernel<<<256, 256, 0, stream>>>(W, wb);
  lorentz_kernel<<<65536 / BM, THREADS, 0, stream>>>(x, wb, b, sc, outp);
}